// Round 4
// baseline (176.762 us; speedup 1.0000x reference)
//
#include <hip/hip_runtime.h>

// FlowNetC correlation, B=16 C=256 H=48 W=64, 21x21 displacements (stride 2, +/-20).
// out[b, i*21+j, h, w] = sum_c in1[b,c,h,w] * in2[b,c,h+2i-20,w+2j-20]  (zero OOB)
//
// v4: MFMA path. v3 was LDS-pipe-bound (LDS demand ~2.8x VALU issue, MfmaUtil=0).
// Kernel T: transpose+f16-pack both inputs into d_ws as [b][h][parity][w' 32][c 256]
//           (w parity split because displacement stride is 2).
// Kernel 2: per (b,h): A-frags (in1) -> regs once; per valid oy: banded Gram
//           P[w1',w2'] via 2 par x 2 n-tiles x 16 k of mfma_f32_32x32x16_f16,
//           operands straight from global (no LDS operands at all). OOB w2' lanes
//           get zero-B (= reference's zero padding). Epilogue scatters D into a
//           65-float-stride LDS slab (65 % 32 == 1 -> conflict-free) then does
//           coalesced stores. B-frags double-buffered across oy (static ping-pong).
// Fallback: v3 dot2 kernel if ws_size too small (host-side branch, deterministic).

#define NB 16
#define NC 256
#define NH 48
#define NW 64
#define HW (NH * NW)
#define CHW (NC * NH * NW)
#define ND 21
#define NDISP (ND * ND)

typedef __fp16 half2v __attribute__((ext_vector_type(2)));
typedef _Float16 f16x8 __attribute__((ext_vector_type(8)));
typedef float f32x16 __attribute__((ext_vector_type(16)));

__device__ __forceinline__ unsigned pk2(float lo, float hi) {
    half2v h = __builtin_amdgcn_cvt_pkrtz(lo, hi);
    return __builtin_bit_cast(unsigned, h);
}
__device__ __forceinline__ half2v uph(unsigned u) {
    return __builtin_bit_cast(half2v, u);
}

// ---------------- Kernel T: transpose + pack ----------------
// src [b][c 256][h][w 64] f32 -> dst [(b_local*48+h)*2+par][w' 32][c 256] f16
__global__ void transpose_pack(const float* __restrict__ in1,
                               const float* __restrict__ in2,
                               unsigned* __restrict__ t1,
                               unsigned* __restrict__ t2,
                               int b_base, int nwg48) {
    const int bx = blockIdx.x;
    const int which = (bx >= nwg48) ? 1 : 0;
    const int r = bx - which * nwg48;
    const int b_local = r / NH;
    const int h = r % NH;
    const float* src = (which ? in2 : in1) + (size_t)(b_base + b_local) * CHW + (size_t)h * NW;
    unsigned* dst = which ? t2 : t1;

    const int t = threadIdx.x;
    const int w = t & 63;
    const int wid = t >> 6;
    const int plane = (b_local * NH + h) * 2 + (w & 1);
    unsigned* dp = dst + (size_t)plane * 4096 + (size_t)(w >> 1) * 128;

    #pragma unroll 1
    for (int i = 0; i < 8; ++i) {
        const int c8 = wid * 8 + i;           // c = c8*8 .. c8*8+7
        const float* s = src + (size_t)(c8 * 8) * HW + w;
        float v0 = s[0 * HW], v1 = s[1 * HW], v2 = s[2 * HW], v3 = s[3 * HW];
        float v4 = s[4 * HW], v5 = s[5 * HW], v6 = s[6 * HW], v7 = s[7 * HW];
        uint4 q = make_uint4(pk2(v0, v1), pk2(v2, v3), pk2(v4, v5), pk2(v6, v7));
        *(uint4*)(dp + c8 * 4) = q;
    }
}

// ---------------- Kernel 2: banded-Gram MFMA ----------------
__global__ __launch_bounds__(256, 2)
void corr_mfma(const unsigned* __restrict__ in1T, const unsigned* __restrict__ in2T,
               float* __restrict__ out, int b_base, int nwg) {
    __shared__ float slab[ND * 65];           // stride 65 == 1 mod 32 -> conflict-free

    const int t = threadIdx.x;
    const int lane = t & 63;
    const int wid = t >> 6;
    const int par = wid >> 1;                 // w parity this wave handles
    const int nt = wid & 1;                   // n-tile (w2' block)
    const int ln31 = lane & 31;
    const int kh = lane >> 5;                 // k-half within fragment

    // XCD-chunked swizzle (nwg % 8 == 0 always: nwg = bc*48)
    const int bx = blockIdx.x;
    const int cpx = nwg >> 3;
    const int L = (bx & 7) * cpx + (bx >> 3);
    const int b_local = L / NH;
    const int h = L % NH;
    const int b = b_base + b_local;

    float* out_b = out + (size_t)b * NDISP * HW + (size_t)h * NW;

    // ---- B-lane geometry: w2' = nt*32 - 16 + ln31, valid iff in [0,32) ----
    const int w2p = nt * 32 - 16 + ln31;
    const bool bval = ((unsigned)w2p < 32u);
    const int w2c = bval ? w2p : 0;
    const uint4 z4 = make_uint4(0u, 0u, 0u, 0u);

    // ---- valid oy range ----
    const int lo = (h >= 20) ? 0 : ((21 - h) >> 1);
    const int hi = min(20, (67 - h) >> 1);

#define ZROW(oy_)                                                            \
    do {                                                                     \
        _Pragma("unroll") for (int s_ = 0; s_ < 6; ++s_) {                   \
            int k_ = t + 256 * s_;                                           \
            if (k_ < ND * NW)                                                \
                out_b[(size_t)((oy_) * ND + (k_ >> 6)) * HW + (k_ & 63)] = 0.f; \
        }                                                                    \
    } while (0)

    // zero slabs for OOB oy rows
    #pragma unroll 1
    for (int oy = 0; oy < lo; ++oy) ZROW(oy);
    #pragma unroll 1
    for (int oy = hi + 1; oy < ND; ++oy) ZROW(oy);

    // ---- A-frags to registers (once per block) ----
    uint4 av[16];
    {
        const unsigned* pa = in1T + ((size_t)((b_local * NH + h) * 2 + par)) * 4096 +
                             (size_t)ln31 * 128;
        #pragma unroll
        for (int kk = 0; kk < 16; ++kk)
            av[kk] = *(const uint4*)(pa + (2 * kk + kh) * 4);
    }

#define LOADB(oy_, bv_)                                                      \
    do {                                                                     \
        const int h2_ = h + 2 * (oy_) - 20;                                  \
        const unsigned* pb_ = in2T +                                         \
            ((size_t)((b_local * NH + h2_) * 2 + par)) * 4096 +              \
            (size_t)w2c * 128;                                               \
        _Pragma("unroll") for (int kk = 0; kk < 16; ++kk)                    \
            bv_[kk] = bval ? *(const uint4*)(pb_ + (2 * kk + kh) * 4) : z4;  \
    } while (0)

#define MFMA16(acc_, bv_)                                                    \
    do {                                                                     \
        __builtin_amdgcn_s_setprio(1);                                       \
        _Pragma("unroll") for (int kk = 0; kk < 16; ++kk)                    \
            acc_ = __builtin_amdgcn_mfma_f32_32x32x16_f16(                   \
                __builtin_bit_cast(f16x8, av[kk]),                           \
                __builtin_bit_cast(f16x8, bv_[kk]), acc_, 0, 0, 0);          \
        __builtin_amdgcn_s_setprio(0);                                       \
    } while (0)

    // D layout (32x32): col = lane&31, row = (reg&3) + 8*(reg>>2) + 4*(lane>>5)
#define EPI(oy_, acc_)                                                       \
    do {                                                                     \
        _Pragma("unroll") for (int r_ = 0; r_ < 16; ++r_) {                  \
            const int m_ = (r_ & 3) + 8 * (r_ >> 2) + 4 * kh;                \
            const int j_ = 32 * nt + ln31 - m_ - 6;                          \
            if ((unsigned)j_ < (unsigned)ND)                                 \
                slab[j_ * 65 + 2 * m_ + par] = acc_[r_];                     \
        }                                                                    \
        __syncthreads();                                                     \
        _Pragma("unroll") for (int s_ = 0; s_ < 6; ++s_) {                   \
            int k_ = t + 256 * s_;                                           \
            if (k_ < ND * NW) {                                              \
                int j_ = k_ >> 6, w_ = k_ & 63;                              \
                out_b[(size_t)((oy_) * ND + j_) * HW + w_] = slab[j_ * 65 + w_]; \
            }                                                                \
        }                                                                    \
        __syncthreads();                                                     \
    } while (0)

    // ---- pipelined oy loop: B-frags double-buffered (static ping-pong) ----
    uint4 bvA[16], bvB[16];
    int oy = lo;
    LOADB(oy, bvA);
    while (true) {
        if (oy + 1 <= hi) LOADB(oy + 1, bvB);   // prefetch before consuming bvA
        {
            f32x16 acc;
            #pragma unroll
            for (int i = 0; i < 16; ++i) acc[i] = 0.f;
            MFMA16(acc, bvA);
            EPI(oy, acc);
        }
        if (++oy > hi) break;
        if (oy + 1 <= hi) LOADB(oy + 1, bvA);
        {
            f32x16 acc;
            #pragma unroll
            for (int i = 0; i < 16; ++i) acc[i] = 0.f;
            MFMA16(acc, bvB);
            EPI(oy, acc);
        }
        if (++oy > hi) break;
    }
#undef ZROW
#undef LOADB
#undef MFMA16
#undef EPI
}

// ---------------- Fallback: v3 dot2 kernel (proven, 157us) ----------------
#define NCB 16
#define IN1_P 36
#define IN1_C2 (2 * IN1_P)
#define IN1_WORDS (128 * IN1_C2)
#define IN2_P 52
#define IN2_C2 (2 * IN2_P)
#define IN2_WAVE (8 * IN2_C2)
#define LDS_WORDS (IN1_WORDS + 4 * IN2_WAVE)

#if defined(__has_builtin)
#if __has_builtin(__builtin_amdgcn_fdot2)
#define HAVE_FDOT2 1
#endif
#endif
__device__ __forceinline__ float fdot2f(half2v a, half2v b, float c) {
#ifdef HAVE_FDOT2
    return __builtin_amdgcn_fdot2(a, b, c, false);
#else
    return c + (float)a.x * (float)b.x + (float)a.y * (float)b.y;
#endif
}
#define WW(u, m) uph(((m) & 1) ? wn[u][(m) >> 1].y : wn[u][(m) >> 1].x)

__global__ __launch_bounds__(256, 3)
void corr_kernel(const float* __restrict__ in1, const float* __restrict__ in2,
                 float* __restrict__ out) {
    __shared__ __align__(16) unsigned lds[LDS_WORDS];
    unsigned* in1_s = lds;
    const int t = threadIdx.x;
    const int lane = t & 63;
    const int wid = t >> 6;
    const int tw = lane & 7;
    const int oh = (lane >> 3) & 1;
    const int p = (lane >> 4) & 1;
    const int chalf = (lane >> 5) & 1;
    unsigned* in2w = lds + IN1_WORDS + wid * IN2_WAVE;
    const int bx = blockIdx.x;
    const int L = (bx & 7) * 96 + (bx >> 3);
    const int b = L / NH;
    const int h = L % NH;
    const float* in1_row = in1 + (size_t)b * CHW + (size_t)h * NW;
    for (int i = lane; i < IN2_WAVE; i += 64) in2w[i] = 0u;
    #pragma unroll 1
    for (int j = 0; j < 8; ++j) {
        const int task = t + 256 * j;
        const int c2 = task >> 4;
        const int c4 = task & 15;
        const float4 u0 = ((const float4*)(in1_row + (size_t)(2 * c2) * HW))[c4];
        const float4 u1 = ((const float4*)(in1_row + (size_t)(2 * c2 + 1) * HW))[c4];
        unsigned* d0 = &in1_s[c2 * IN1_C2 + 2 * c4];
        *(uint2*)&d0[0] = make_uint2(pk2(u0.x, u1.x), pk2(u0.z, u1.z));
        *(uint2*)&d0[IN1_P] = make_uint2(pk2(u0.y, u1.y), pk2(u0.w, u1.w));
    }
    __syncthreads();
    const int q = lane >> 4;
    const int col4 = lane & 15;
    const int lo = (h >= 20) ? 0 : ((21 - h) >> 1);
    const int hi = min(20, (67 - h) >> 1);
    const int nv = hi - lo + 1;
    const int rot = (wid + h) & 3;
    #pragma unroll 1
    for (int oy = rot; oy < ND; oy += 4) {
        if (oy >= lo && oy <= hi) continue;
        float* orow = out + ((size_t)(b * NDISP + oy * ND) * NH + h) * NW;
        #pragma unroll
        for (int o = 0; o < ND; ++o) orow[(size_t)o * HW + lane] = 0.f;
    }
    #pragma unroll 1
    for (int k = rot; k < nv; k += 4) {
        const int oyi = lo + k;
        const int row = h + 2 * oyi - 20;
        float* orow = out + ((size_t)(b * NDISP + oyi * ND) * NH + h) * NW;
        const float* in2_row = in2 + (size_t)b * CHW + (size_t)row * NW;
        float acc[11][4];
        #pragma unroll
        for (int ol = 0; ol < 11; ++ol)
            #pragma unroll
            for (int i = 0; i < 4; ++i) acc[ol][i] = 0.f;
        float4 pre[4];
        {
            const float* s0 = in2_row + (size_t)(2 * q) * HW;
            const float* s1 = in2_row + (size_t)(2 * (q + 4)) * HW;
            pre[0] = ((const float4*)s0)[col4];
            pre[1] = ((const float4*)(s0 + HW))[col4];
            pre[2] = ((const float4*)s1)[col4];
            pre[3] = ((const float4*)(s1 + HW))[col4];
        }
        #pragma unroll 1
        for (int cb = 0; cb < NCB; ++cb) {
            {
                unsigned* da = &in2w[q * IN2_C2 + 2 * col4 + 10];
                unsigned* db = &in2w[(q + 4) * IN2_C2 + 2 * col4 + 10];
                *(uint2*)&da[0] = make_uint2(pk2(pre[0].x, pre[1].x), pk2(pre[0].z, pre[1].z));
                *(uint2*)&da[IN2_P] = make_uint2(pk2(pre[0].y, pre[1].y), pk2(pre[0].w, pre[1].w));
                *(uint2*)&db[0] = make_uint2(pk2(pre[2].x, pre[3].x), pk2(pre[2].z, pre[3].z));
                *(uint2*)&db[IN2_P] = make_uint2(pk2(pre[2].y, pre[3].y), pk2(pre[2].w, pre[3].w));
            }
            if (cb + 1 < NCB) {
                const float* srcn = in2_row + (size_t)((cb + 1) * 16) * HW;
                const float* s0 = srcn + (size_t)(2 * q) * HW;
                const float* s1 = srcn + (size_t)(2 * (q + 4)) * HW;
                pre[0] = ((const float4*)s0)[col4];
                pre[1] = ((const float4*)(s0 + HW))[col4];
                pre[2] = ((const float4*)s1)[col4];
                pre[3] = ((const float4*)(s1 + HW))[col4];
            }
            uint4 avv[4];
            uint2 wn[4][7];
            {
                const unsigned* base1 = &in1_s[(cb * 8 + chalf) * IN1_C2 + p * IN1_P + 4 * tw];
                const unsigned* base2 = &in2w[chalf * IN2_C2 + p * IN2_P + 4 * tw + 10 * oh];
                #pragma unroll
                for (int u = 0; u < 4; ++u) {
                    avv[u] = *(const uint4*)(base1 + (size_t)(2 * u) * IN1_C2);
                    #pragma unroll
                    for (int jj = 0; jj < 7; ++jj)
                        wn[u][jj] = *(const uint2*)(base2 + (size_t)(2 * u) * IN2_C2 + 2 * jj);
                }
            }
            #pragma unroll
            for (int u = 0; u < 4; ++u) {
                const half2v a0 = uph(avv[u].x), a1 = uph(avv[u].y);
                const half2v a2 = uph(avv[u].z), a3 = uph(avv[u].w);
                #pragma unroll
                for (int ol = 0; ol < 11; ++ol) {
                    acc[ol][0] = fdot2f(a0, WW(u, ol + 0), acc[ol][0]);
                    acc[ol][1] = fdot2f(a1, WW(u, ol + 1), acc[ol][1]);
                    acc[ol][2] = fdot2f(a2, WW(u, ol + 2), acc[ol][2]);
                    acc[ol][3] = fdot2f(a3, WW(u, ol + 3), acc[ol][3]);
                }
            }
        }
        #pragma unroll
        for (int ol = 0; ol < 11; ++ol)
            #pragma unroll
            for (int i = 0; i < 4; ++i) {
                float v = acc[ol][i];
                v += __shfl_xor(v, 32);
                acc[ol][i] = v;
            }
        if (chalf == 0) {
            #pragma unroll
            for (int ol = 0; ol < 11; ++ol) {
                if (oh == 1 && ol == 0) continue;
                const int og = 10 * oh + ol;
                #pragma unroll
                for (int i = 0; i < 4; ++i)
                    orow[(size_t)og * HW + (p + 8 * tw + 2 * i)] = acc[ol][i];
            }
        }
    }
}

// ---------------- host ----------------
extern "C" void kernel_launch(void* const* d_in, const int* in_sizes, int n_in,
                              void* d_out, int out_size, void* d_ws, size_t ws_size,
                              hipStream_t stream) {
    const float* in1 = (const float*)d_in[0];
    const float* in2 = (const float*)d_in[1];
    float* out = (float*)d_out;

    // bytes per b per input in transposed-f16 form: 48*2*32*256*2 = 1572864
    const size_t per_b = 1572864;
    int bc = 0;
    const int cands[5] = {16, 8, 4, 2, 1};
    for (int i = 0; i < 5; ++i) {
        if ((size_t)cands[i] * 2 * per_b <= ws_size) { bc = cands[i]; break; }
    }
    if (bc == 0) {
        corr_kernel<<<dim3(NB * NH), dim3(256), 0, stream>>>(in1, in2, out);
        return;
    }
    unsigned* t1 = (unsigned*)d_ws;
    unsigned* t2 = t1 + (size_t)bc * NH * 2 * 4096;
    const int nwg48 = bc * NH;
    for (int b0 = 0; b0 < NB; b0 += bc) {
        transpose_pack<<<dim3(2 * nwg48), dim3(256), 0, stream>>>(in1, in2, t1, t2, b0, nwg48);
        corr_mfma<<<dim3(nwg48), dim3(256), 0, stream>>>(t1, t2, out, b0, nwg48);
    }
}